// Round 5
// baseline (686.445 us; speedup 1.0000x reference)
//
#include <hip/hip_runtime.h>
#include <hip/hip_bf16.h>
#include <math.h>

#define B_ 4
#define L_ 1024
#define H_ 8
#define E_ 64
#define N_ 1024
#define NF_ 513            // rfft bins for N=1024
#define SCALE_ 0.125f      // 1/sqrt(E)
#define HE_ (H_ * E_)

__device__ __forceinline__ int brev10(int x) {
    return (int)(__brev((unsigned)x) >> 22);
}

// Compact per-stage twiddles: stage with half-span S=2^ls stores its S entries
// at offset S-1, entry pos = (cos, sin)(pi*pos/S). Reads are consecutive or
// broadcast -> conflict-free. 1023 entries total.
__device__ __forceinline__ void fill_tw(float2* tw, int t) {
    for (int i = t; i < 1023; i += 256) {
        const int v = i + 1;
        const int ls = 31 - __clz(v);
        const int S = 1 << ls;
        float sv, cv;
        sincosf(3.14159265358979323846f * (float)(v - S) / (float)S, &sv, &cv);
        tw[i] = make_float2(cv, sv);
    }
}

// Radix-2 DIT: bit-reversed input -> natural output. dir=-1 fwd, +1 inv (unnorm).
// 256 threads, 1024 points, interleaved float2. Ends with __syncthreads().
__device__ __forceinline__ void fft_dit(float2* z, const float2* tw, int t, float dir) {
    #pragma unroll
    for (int ls = 0; ls <= 9; ++ls) {
        const int S = 1 << ls;
        #pragma unroll
        for (int jj = 0; jj < 2; ++jj) {
            const int j = t + jj * 256;
            const int pos = j & (S - 1);
            const int i1 = ((j >> ls) << (ls + 1)) + pos;
            const int i2 = i1 + S;
            const float2 w = tw[S - 1 + pos];
            const float wr = w.x, wi = dir * w.y;
            const float2 u = z[i1], v = z[i2];
            const float tr = v.x * wr - v.y * wi;
            const float ti = v.x * wi + v.y * wr;
            z[i1] = make_float2(u.x + tr, u.y + ti);
            z[i2] = make_float2(u.x - tr, u.y - ti);
        }
        __syncthreads();
    }
}

// Radix-2 DIF: natural input -> bit-reversed output. dir=-1 fwd, +1 inv (unnorm).
__device__ __forceinline__ void fft_dif(float2* z, const float2* tw, int t, float dir) {
    #pragma unroll
    for (int ls = 9; ls >= 0; --ls) {
        const int S = 1 << ls;
        #pragma unroll
        for (int jj = 0; jj < 2; ++jj) {
            const int j = t + jj * 256;
            const int pos = j & (S - 1);
            const int i1 = ((j >> ls) << (ls + 1)) + pos;
            const int i2 = i1 + S;
            const float2 w = tw[S - 1 + pos];
            const float wr = w.x, wi = dir * w.y;
            const float2 u = z[i1], v = z[i2];
            z[i1] = make_float2(u.x + v.x, u.y + v.y);
            const float dr = u.x - v.x, di = u.y - v.y;
            z[i2] = make_float2(dr * wr - di * wi, dr * wi + di * wr);
        }
        __syncthreads();
    }
}

// Kernel 0: reciprocal L2 norms of all q-rows and k-rows.
__global__ __launch_bounds__(256) void k_norms(const float* __restrict__ Q,
                                               const float* __restrict__ K,
                                               float* __restrict__ qninv,
                                               float* __restrict__ kninv) {
    const int n = B_ * L_ * H_;
    const int i = blockIdx.x * 256 + threadIdx.x;
    if (i >= 2 * n) return;
    const float* p = (i < n) ? (Q + (size_t)i * E_) : (K + (size_t)(i - n) * E_);
    float ss = 0.0f;
    #pragma unroll
    for (int j = 0; j < 16; ++j) {
        const float4 v = *(const float4*)(p + j * 4);
        ss += v.x * v.x + v.y * v.y + v.z * v.z + v.w * v.w;
    }
    const float r = rsqrtf(ss);
    if (i < n) qninv[i] = r; else kninv[i - n] = r;
}

// Kernel 1: block = one (b,h) x 16 q-rows. Two passes of 8 rows (pp loop
// unroll 1: acc lives inside the pass body; pr loop fully unrolled so all
// acc indices are compile-time static — runtime indexing demotes to scratch).
// launch_bounds (256,3): VGPR cap ~170. History: (256,4) -> 64-cap, 895 MB
// spill; (256,2) -> compiler picked 128, still ~360 B/thread spill (189 MB
// WRITE, 713 MB FETCH). Peak pressure is ~130 (acc 32 + 2x8 K-float4 64 +
// misc); cap 170 fits with slack and gives 12 waves/CU.
__global__ __launch_bounds__(256, 3) void k_qkfft(const float* __restrict__ Q,
                                                  const float* __restrict__ K,
                                                  const float* __restrict__ qninv,
                                                  const float* __restrict__ kninv,
                                                  float* __restrict__ G) {
    __shared__ float2 s_z[1024];    // 8 KB FFT buffer (interleaved)
    __shared__ float2 s_tw[1024];   // 8 KB compact twiddles
    __shared__ float s_acc[NF_];
    __shared__ float s_red[16];

    const int t = threadIdx.x;
    const int bid = blockIdx.x;
    const int bh = bid >> 6;        // consecutive blocks share (b,h) -> L2 reuse of K
    const int chunk = bid & 63;
    const int b = bh >> 3, h = bh & 7;
    const int l0 = chunk * 16;

    fill_tw(s_tw, t);
    for (int kk = t; kk < NF_; kk += 256) s_acc[kk] = 0.0f;

    // thread's 4 source indices s' = brev10(slot), slot = sb*256+t  (so the
    // sim store into the DIT input buffer is linear / conflict-free)
    int sp[4];
    float knv[4];
    #pragma unroll
    for (int sb = 0; sb < 4; ++sb) {
        sp[sb] = brev10(sb * 256 + t);
        knv[sb] = kninv[((size_t)b * L_ + sp[sb]) * H_ + h];
    }
    __syncthreads();

    #pragma unroll 1
    for (int pp = 0; pp < 2; ++pp) {
        const float* qbase = Q + ((size_t)b * L_ + l0 + pp * 8) * HE_ + h * E_;

        float acc[4][8];
        #pragma unroll
        for (int sb = 0; sb < 4; ++sb)
            #pragma unroll
            for (int r = 0; r < 8; ++r) acc[sb][r] = 0.0f;

        #pragma unroll
        for (int sbg = 0; sbg < 2; ++sbg) {
            const int sa = 2 * sbg, sbn = 2 * sbg + 1;
            const float* kap = K + ((size_t)b * L_ + sp[sa]) * HE_ + h * E_;
            const float* kbp = K + ((size_t)b * L_ + sp[sbn]) * HE_ + h * E_;
            #pragma unroll
            for (int ec = 0; ec < 4; ++ec) {
                const float4 ka0 = *(const float4*)(kap + ec * 16 + 0);
                const float4 ka1 = *(const float4*)(kap + ec * 16 + 4);
                const float4 ka2 = *(const float4*)(kap + ec * 16 + 8);
                const float4 ka3 = *(const float4*)(kap + ec * 16 + 12);
                const float4 kb0 = *(const float4*)(kbp + ec * 16 + 0);
                const float4 kb1 = *(const float4*)(kbp + ec * 16 + 4);
                const float4 kb2 = *(const float4*)(kbp + ec * 16 + 8);
                const float4 kb3 = *(const float4*)(kbp + ec * 16 + 12);
                #pragma unroll
                for (int r = 0; r < 8; ++r) {
                    const float* qp = qbase + r * HE_ + ec * 16;   // uniform -> s_load
                    const float4 q0 = *(const float4*)(qp + 0);
                    const float4 q1 = *(const float4*)(qp + 4);
                    const float4 q2 = *(const float4*)(qp + 8);
                    const float4 q3 = *(const float4*)(qp + 12);
                    acc[sa][r] += q0.x * ka0.x + q0.y * ka0.y + q0.z * ka0.z + q0.w * ka0.w
                                + q1.x * ka1.x + q1.y * ka1.y + q1.z * ka1.z + q1.w * ka1.w
                                + q2.x * ka2.x + q2.y * ka2.y + q2.z * ka2.z + q2.w * ka2.w
                                + q3.x * ka3.x + q3.y * ka3.y + q3.z * ka3.z + q3.w * ka3.w;
                    acc[sbn][r] += q0.x * kb0.x + q0.y * kb0.y + q0.z * kb0.z + q0.w * kb0.w
                                 + q1.x * kb1.x + q1.y * kb1.y + q1.z * kb1.z + q1.w * kb1.w
                                 + q2.x * kb2.x + q2.y * kb2.y + q2.z * kb2.z + q2.w * kb2.w
                                 + q3.x * kb3.x + q3.y * kb3.y + q3.z * kb3.z + q3.w * kb3.w;
                }
            }
        }

        float qn[8];
        #pragma unroll
        for (int r = 0; r < 8; ++r)
            qn[r] = qninv[((size_t)b * L_ + l0 + pp * 8 + r) * H_ + h];  // uniform

        #pragma unroll
        for (int pr = 0; pr < 4; ++pr) {
            __syncthreads();   // prior extraction/s_red reads complete
            #pragma unroll
            for (int sb = 0; sb < 4; ++sb) {
                const float sA = __expf(acc[sb][2 * pr]     * qn[2 * pr]     * knv[sb]);
                const float sB = __expf(acc[sb][2 * pr + 1] * qn[2 * pr + 1] * knv[sb]);
                s_z[sb * 256 + t] = make_float2(sA, sB);
            }
            __syncthreads();
            fft_dit(s_z, s_tw, t, -1.0f);   // natural-order X

            // Re F_A[k] = (ReX[k]+ReX[N-k])/2 ; Re F_B[k] = (ImX[k]+ImX[N-k])/2
            const float2 X0  = s_z[t];
            const float2 X0n = s_z[(N_ - t) & (N_ - 1)];
            const float2 X1  = s_z[t + 256];
            const float2 X1n = s_z[768 - t];
            const float a0 = SCALE_ * 0.5f * (X0.x + X0n.x);
            const float b0 = SCALE_ * 0.5f * (X0.y + X0n.y);
            const float a1 = SCALE_ * 0.5f * (X1.x + X1n.x);
            const float b1 = SCALE_ * 0.5f * (X1.y + X1n.y);
            float a2 = -1e30f, b2 = -1e30f;
            if (t == 0) {
                const float2 Xm = s_z[512];
                a2 = SCALE_ * Xm.x;
                b2 = SCALE_ * Xm.y;
            }

            float mA = fmaxf(fmaxf(a0, a1), a2);
            float mB = fmaxf(fmaxf(b0, b1), b2);
            #pragma unroll
            for (int off = 32; off > 0; off >>= 1) {
                mA = fmaxf(mA, __shfl_xor(mA, off));
                mB = fmaxf(mB, __shfl_xor(mB, off));
            }
            const int lane = t & 63, wid = t >> 6;
            if (lane == 0) { s_red[wid] = mA; s_red[4 + wid] = mB; }
            __syncthreads();
            mA = fmaxf(fmaxf(s_red[0], s_red[1]), fmaxf(s_red[2], s_red[3]));
            mB = fmaxf(fmaxf(s_red[4], s_red[5]), fmaxf(s_red[6], s_red[7]));

            const float pA0 = __expf(a0 - mA), pA1 = __expf(a1 - mA);
            const float pB0 = __expf(b0 - mB), pB1 = __expf(b1 - mB);
            const float pA2 = (t == 0) ? __expf(a2 - mA) : 0.0f;
            const float pB2 = (t == 0) ? __expf(b2 - mB) : 0.0f;
            float sA = pA0 + pA1 + pA2, sB = pB0 + pB1 + pB2;
            #pragma unroll
            for (int off = 32; off > 0; off >>= 1) {
                sA += __shfl_xor(sA, off);
                sB += __shfl_xor(sB, off);
            }
            __syncthreads();
            if (lane == 0) { s_red[8 + wid] = sA; s_red[12 + wid] = sB; }
            __syncthreads();
            sA = s_red[8] + s_red[9] + s_red[10] + s_red[11];
            sB = s_red[12] + s_red[13] + s_red[14] + s_red[15];
            const float iA = 1.0f / sA, iB = 1.0f / sB;

            s_acc[t]       += pA0 * iA + pB0 * iB;
            s_acc[t + 256] += pA1 * iA + pB1 * iB;
            if (t == 0) s_acc[512] += pA2 * iA + pB2 * iB;
        }
    }
    __syncthreads();

    float* Gp = G + (size_t)bh * NF_;
    for (int kk = t; kk < NF_; kk += 256) atomicAdd(&Gp[kk], s_acc[kk]);
}

// Kernel 2: A[b,h,:] = softmax(G[b,h,:]) over 513 bins.
__global__ __launch_bounds__(256) void k_softA(const float* __restrict__ G,
                                               float* __restrict__ A) {
    __shared__ float s_red[16];
    const int bh = blockIdx.x, t = threadIdx.x;
    const float* Gp = G + (size_t)bh * NF_;
    const float g0 = Gp[t];
    const float g1 = Gp[t + 256];
    const float g2 = (t == 0) ? Gp[512] : -1e30f;
    float m = fmaxf(fmaxf(g0, g1), g2);
    #pragma unroll
    for (int off = 32; off > 0; off >>= 1) m = fmaxf(m, __shfl_xor(m, off));
    const int lane = t & 63, wid = t >> 6;
    if (lane == 0) s_red[wid] = m;
    __syncthreads();
    m = fmaxf(fmaxf(s_red[0], s_red[1]), fmaxf(s_red[2], s_red[3]));
    const float p0 = __expf(g0 - m), p1 = __expf(g1 - m);
    const float p2 = (t == 0) ? __expf(g2 - m) : 0.0f;
    float s = p0 + p1 + p2;
    #pragma unroll
    for (int off = 32; off > 0; off >>= 1) s += __shfl_xor(s, off);
    __syncthreads();
    if (lane == 0) s_red[4 + wid] = s;
    __syncthreads();
    s = s_red[4] + s_red[5] + s_red[6] + s_red[7];
    const float inv = 1.0f / s;
    float* Ap = A + (size_t)bh * NF_;
    Ap[t] = p0 * inv;
    Ap[t + 256] = p1 * inv;
    if (t == 0) Ap[512] = p2 * inv;
}

// Kernel 3: block = one (b,h) x 2 e-channels. Stage V at bitrev positions,
// DIT fwd -> natural X; Hermitian manipulation in natural order (conflict-free);
// DIF inverse (natural in -> bitrev out); write Out[l=brev10(pos)].
__global__ __launch_bounds__(256) void k_vfft(const float* __restrict__ V,
                                              const float* __restrict__ A,
                                              float* __restrict__ Out) {
    __shared__ float2 s_z[1024];
    __shared__ float2 s_w[1024];
    __shared__ float2 s_tw[1024];
    __shared__ float s_A[NF_];

    const int t = threadIdx.x;
    const int bid = blockIdx.x;
    const int bh = bid >> 5, ep = bid & 31;
    const int b = bh >> 3, h = bh & 7;
    const int e0 = ep * 2;

    fill_tw(s_tw, t);
    for (int kk = t; kk < NF_; kk += 256) s_A[kk] = A[(size_t)bh * NF_ + kk];
    #pragma unroll
    for (int jj = 0; jj < 4; ++jj) {
        const int s = jj * 256 + t;
        const float* vp = V + (((size_t)b * L_ + s) * H_ + h) * E_ + e0;
        s_z[brev10(s)] = make_float2(vp[0], vp[1]);
    }
    __syncthreads();

    fft_dit(s_z, s_tw, t, -1.0f);   // natural-order X

    #pragma unroll
    for (int jj = 0; jj < 4; ++jj) {
        const int k = jj * 256 + t;
        const int m = (k <= 512) ? k : (N_ - k);
        const float sgn = (k <= 512) ? 1.0f : -1.0f;
        const int mp = (N_ - m) & (N_ - 1);
        const float2 X1 = s_z[m];
        const float2 X2 = s_z[mp];
        const float reV1 = 0.5f * (X1.x + X2.x);
        const float imV1 = 0.5f * (X1.y - X2.y);
        const float reV2 = 0.5f * (X1.y + X2.y);
        const float imV2 = 0.5f * (X2.x - X1.x);
        const float a = s_A[m];
        s_w[k] = make_float2(a * reV1 - sgn * imV2, sgn * imV1 + a * reV2);
    }
    __syncthreads();

    fft_dif(s_w, s_tw, t, +1.0f);   // unnormalized inverse, bitrev output

    const float invN = 1.0f / (float)N_;
    #pragma unroll
    for (int jj = 0; jj < 4; ++jj) {
        const int p = jj * 256 + t;
        const int l = brev10(p);
        const size_t o = (((size_t)b * L_ + l) * E_ + e0) * H_ + h;
        Out[o] = s_w[p].x * invN;        // e0   -> Re
        Out[o + H_] = s_w[p].y * invN;   // e0+1 -> Im
    }
}

extern "C" void kernel_launch(void* const* d_in, const int* in_sizes, int n_in,
                              void* d_out, int out_size, void* d_ws, size_t ws_size,
                              hipStream_t stream) {
    const float* Q = (const float*)d_in[0];
    const float* K = (const float*)d_in[1];
    const float* V = (const float*)d_in[2];
    float* out = (float*)d_out;

    float* ws = (float*)d_ws;
    float* qninv = ws;                       // B*L*H
    float* kninv = qninv + B_ * L_ * H_;     // B*L*H
    float* G     = kninv + B_ * L_ * H_;     // B*H*NF
    float* A     = G + B_ * H_ * NF_;        // B*H*NF

    hipMemsetAsync(G, 0, (size_t)B_ * H_ * NF_ * sizeof(float), stream);
    k_norms<<<(2 * B_ * L_ * H_ + 255) / 256, 256, 0, stream>>>(Q, K, qninv, kninv);
    k_qkfft<<<B_ * H_ * (L_ / 16), 256, 0, stream>>>(Q, K, qninv, kninv, G);
    k_softA<<<B_ * H_, 256, 0, stream>>>(G, A);
    k_vfft<<<B_ * H_ * (E_ / 2), 256, 0, stream>>>(V, A, out);
}

// Round 6
// 284.629 us; speedup vs baseline: 2.4117x; 2.4117x over previous
//
#include <hip/hip_runtime.h>
#include <hip/hip_bf16.h>
#include <math.h>

#define B_ 4
#define L_ 1024
#define H_ 8
#define E_ 64
#define N_ 1024
#define NF_ 513            // rfft bins for N=1024
#define SCALE_ 0.125f      // 1/sqrt(E)
#define HE_ (H_ * E_)

__device__ __forceinline__ int brev10(int x) {
    return (int)(__brev((unsigned)x) >> 22);
}

// Compact per-stage twiddles: stage with half-span S=2^ls stores its S entries
// at offset S-1, entry pos = (cos, sin)(pi*pos/S). Reads are consecutive or
// broadcast -> conflict-free. 1023 entries total.
__device__ __forceinline__ void fill_tw(float2* tw, int t) {
    for (int i = t; i < 1023; i += 256) {
        const int v = i + 1;
        const int ls = 31 - __clz(v);
        const int S = 1 << ls;
        float sv, cv;
        sincosf(3.14159265358979323846f * (float)(v - S) / (float)S, &sv, &cv);
        tw[i] = make_float2(cv, sv);
    }
}

// Radix-2 DIT: bit-reversed input -> natural output. dir=-1 fwd, +1 inv (unnorm).
// 256 threads, 1024 points, interleaved float2. Ends with __syncthreads().
__device__ __forceinline__ void fft_dit(float2* z, const float2* tw, int t, float dir) {
    #pragma unroll
    for (int ls = 0; ls <= 9; ++ls) {
        const int S = 1 << ls;
        #pragma unroll
        for (int jj = 0; jj < 2; ++jj) {
            const int j = t + jj * 256;
            const int pos = j & (S - 1);
            const int i1 = ((j >> ls) << (ls + 1)) + pos;
            const int i2 = i1 + S;
            const float2 w = tw[S - 1 + pos];
            const float wr = w.x, wi = dir * w.y;
            const float2 u = z[i1], v = z[i2];
            const float tr = v.x * wr - v.y * wi;
            const float ti = v.x * wi + v.y * wr;
            z[i1] = make_float2(u.x + tr, u.y + ti);
            z[i2] = make_float2(u.x - tr, u.y - ti);
        }
        __syncthreads();
    }
}

// Radix-2 DIF: natural input -> bit-reversed output. dir=-1 fwd, +1 inv (unnorm).
__device__ __forceinline__ void fft_dif(float2* z, const float2* tw, int t, float dir) {
    #pragma unroll
    for (int ls = 9; ls >= 0; --ls) {
        const int S = 1 << ls;
        #pragma unroll
        for (int jj = 0; jj < 2; ++jj) {
            const int j = t + jj * 256;
            const int pos = j & (S - 1);
            const int i1 = ((j >> ls) << (ls + 1)) + pos;
            const int i2 = i1 + S;
            const float2 w = tw[S - 1 + pos];
            const float wr = w.x, wi = dir * w.y;
            const float2 u = z[i1], v = z[i2];
            z[i1] = make_float2(u.x + v.x, u.y + v.y);
            const float dr = u.x - v.x, di = u.y - v.y;
            z[i2] = make_float2(dr * wr - di * wi, dr * wi + di * wr);
        }
        __syncthreads();
    }
}

// Kernel 0: reciprocal L2 norms of all q-rows and k-rows.
__global__ __launch_bounds__(256) void k_norms(const float* __restrict__ Q,
                                               const float* __restrict__ K,
                                               float* __restrict__ qninv,
                                               float* __restrict__ kninv) {
    const int n = B_ * L_ * H_;
    const int i = blockIdx.x * 256 + threadIdx.x;
    if (i >= 2 * n) return;
    const float* p = (i < n) ? (Q + (size_t)i * E_) : (K + (size_t)(i - n) * E_);
    float ss = 0.0f;
    #pragma unroll
    for (int j = 0; j < 16; ++j) {
        const float4 v = *(const float4*)(p + j * 4);
        ss += v.x * v.x + v.y * v.y + v.z * v.z + v.w * v.w;
    }
    const float r = rsqrtf(ss);
    if (i < n) qninv[i] = r; else kninv[i - n] = r;
}

// Kernel 1: block = one (b,h) x 16 q-rows. Two passes of 8 rows.
// Dot phase: ONE K row at a time (sb outer) -> live set acc[4][8]=32 +
// 16-float K chunk = ~70 VGPRs (round-5's paired-row version peaked ~130 and
// the allocator spilled at every cap tried). Q via uniform s_load (no VGPR).
// amdgpu_waves_per_eu(2,4): max=4 pins the backend's occupancy target so it
// stops spilling registers to chase 6+ waves/EU (round-5: chose 84 VGPR +
// 373 MB scratch despite a 170 cap).
__global__ __attribute__((amdgpu_flat_work_group_size(256, 256), amdgpu_waves_per_eu(2, 4)))
void k_qkfft(const float* __restrict__ Q,
             const float* __restrict__ K,
             const float* __restrict__ qninv,
             const float* __restrict__ kninv,
             float* __restrict__ G) {
    __shared__ float2 s_z[1024];    // 8 KB FFT buffer (interleaved)
    __shared__ float2 s_tw[1024];   // 8 KB compact twiddles
    __shared__ float s_acc[NF_];
    __shared__ float s_red[16];

    const int t = threadIdx.x;
    const int bid = blockIdx.x;
    const int bh = bid >> 6;        // consecutive blocks share (b,h) -> L2 reuse of K
    const int chunk = bid & 63;
    const int b = bh >> 3, h = bh & 7;
    const int l0 = chunk * 16;

    fill_tw(s_tw, t);
    for (int kk = t; kk < NF_; kk += 256) s_acc[kk] = 0.0f;

    // thread's 4 source indices s' = brev10(slot), slot = sb*256+t  (so the
    // sim store into the DIT input buffer is linear / conflict-free)
    int sp[4];
    float knv[4];
    #pragma unroll
    for (int sb = 0; sb < 4; ++sb) {
        sp[sb] = brev10(sb * 256 + t);
        knv[sb] = kninv[((size_t)b * L_ + sp[sb]) * H_ + h];
    }
    __syncthreads();

    #pragma unroll 1
    for (int pp = 0; pp < 2; ++pp) {
        const float* qbase = Q + ((size_t)b * L_ + l0 + pp * 8) * HE_ + h * E_;

        float acc[4][8];
        #pragma unroll
        for (int sb = 0; sb < 4; ++sb)
            #pragma unroll
            for (int r = 0; r < 8; ++r) acc[sb][r] = 0.0f;

        #pragma unroll 1
        for (int sb = 0; sb < 4; ++sb) {
            const float* kp = K + ((size_t)b * L_ + sp[sb]) * HE_ + h * E_;
            #pragma unroll
            for (int ec = 0; ec < 4; ++ec) {
                const float4 k0 = *(const float4*)(kp + ec * 16 + 0);
                const float4 k1 = *(const float4*)(kp + ec * 16 + 4);
                const float4 k2 = *(const float4*)(kp + ec * 16 + 8);
                const float4 k3 = *(const float4*)(kp + ec * 16 + 12);
                #pragma unroll
                for (int r = 0; r < 8; ++r) {
                    const float* qp = qbase + r * HE_ + ec * 16;   // uniform -> s_load
                    const float4 q0 = *(const float4*)(qp + 0);
                    const float4 q1 = *(const float4*)(qp + 4);
                    const float4 q2 = *(const float4*)(qp + 8);
                    const float4 q3 = *(const float4*)(qp + 12);
                    acc[sb][r] += q0.x * k0.x + q0.y * k0.y + q0.z * k0.z + q0.w * k0.w
                                + q1.x * k1.x + q1.y * k1.y + q1.z * k1.z + q1.w * k1.w
                                + q2.x * k2.x + q2.y * k2.y + q2.z * k2.z + q2.w * k2.w
                                + q3.x * k3.x + q3.y * k3.y + q3.z * k3.z + q3.w * k3.w;
                }
            }
        }

        float qn[8];
        #pragma unroll
        for (int r = 0; r < 8; ++r)
            qn[r] = qninv[((size_t)b * L_ + l0 + pp * 8 + r) * H_ + h];  // uniform

        #pragma unroll
        for (int pr = 0; pr < 4; ++pr) {
            __syncthreads();   // prior extraction/s_red reads complete
            #pragma unroll
            for (int sb = 0; sb < 4; ++sb) {
                const float sA = __expf(acc[sb][2 * pr]     * qn[2 * pr]     * knv[sb]);
                const float sB = __expf(acc[sb][2 * pr + 1] * qn[2 * pr + 1] * knv[sb]);
                s_z[sb * 256 + t] = make_float2(sA, sB);
            }
            __syncthreads();
            fft_dit(s_z, s_tw, t, -1.0f);   // natural-order X

            // Re F_A[k] = (ReX[k]+ReX[N-k])/2 ; Re F_B[k] = (ImX[k]+ImX[N-k])/2
            const float2 X0  = s_z[t];
            const float2 X0n = s_z[(N_ - t) & (N_ - 1)];
            const float2 X1  = s_z[t + 256];
            const float2 X1n = s_z[768 - t];
            const float a0 = SCALE_ * 0.5f * (X0.x + X0n.x);
            const float b0 = SCALE_ * 0.5f * (X0.y + X0n.y);
            const float a1 = SCALE_ * 0.5f * (X1.x + X1n.x);
            const float b1 = SCALE_ * 0.5f * (X1.y + X1n.y);
            float a2 = -1e30f, b2 = -1e30f;
            if (t == 0) {
                const float2 Xm = s_z[512];
                a2 = SCALE_ * Xm.x;
                b2 = SCALE_ * Xm.y;
            }

            float mA = fmaxf(fmaxf(a0, a1), a2);
            float mB = fmaxf(fmaxf(b0, b1), b2);
            #pragma unroll
            for (int off = 32; off > 0; off >>= 1) {
                mA = fmaxf(mA, __shfl_xor(mA, off));
                mB = fmaxf(mB, __shfl_xor(mB, off));
            }
            const int lane = t & 63, wid = t >> 6;
            if (lane == 0) { s_red[wid] = mA; s_red[4 + wid] = mB; }
            __syncthreads();
            mA = fmaxf(fmaxf(s_red[0], s_red[1]), fmaxf(s_red[2], s_red[3]));
            mB = fmaxf(fmaxf(s_red[4], s_red[5]), fmaxf(s_red[6], s_red[7]));

            const float pA0 = __expf(a0 - mA), pA1 = __expf(a1 - mA);
            const float pB0 = __expf(b0 - mB), pB1 = __expf(b1 - mB);
            const float pA2 = (t == 0) ? __expf(a2 - mA) : 0.0f;
            const float pB2 = (t == 0) ? __expf(b2 - mB) : 0.0f;
            float sA = pA0 + pA1 + pA2, sB = pB0 + pB1 + pB2;
            #pragma unroll
            for (int off = 32; off > 0; off >>= 1) {
                sA += __shfl_xor(sA, off);
                sB += __shfl_xor(sB, off);
            }
            __syncthreads();
            if (lane == 0) { s_red[8 + wid] = sA; s_red[12 + wid] = sB; }
            __syncthreads();
            sA = s_red[8] + s_red[9] + s_red[10] + s_red[11];
            sB = s_red[12] + s_red[13] + s_red[14] + s_red[15];
            const float iA = 1.0f / sA, iB = 1.0f / sB;

            s_acc[t]       += pA0 * iA + pB0 * iB;
            s_acc[t + 256] += pA1 * iA + pB1 * iB;
            if (t == 0) s_acc[512] += pA2 * iA + pB2 * iB;
        }
    }
    __syncthreads();

    float* Gp = G + (size_t)bh * NF_;
    for (int kk = t; kk < NF_; kk += 256) atomicAdd(&Gp[kk], s_acc[kk]);
}

// Kernel 2: A[b,h,:] = softmax(G[b,h,:]) over 513 bins.
__global__ __launch_bounds__(256) void k_softA(const float* __restrict__ G,
                                               float* __restrict__ A) {
    __shared__ float s_red[16];
    const int bh = blockIdx.x, t = threadIdx.x;
    const float* Gp = G + (size_t)bh * NF_;
    const float g0 = Gp[t];
    const float g1 = Gp[t + 256];
    const float g2 = (t == 0) ? Gp[512] : -1e30f;
    float m = fmaxf(fmaxf(g0, g1), g2);
    #pragma unroll
    for (int off = 32; off > 0; off >>= 1) m = fmaxf(m, __shfl_xor(m, off));
    const int lane = t & 63, wid = t >> 6;
    if (lane == 0) s_red[wid] = m;
    __syncthreads();
    m = fmaxf(fmaxf(s_red[0], s_red[1]), fmaxf(s_red[2], s_red[3]));
    const float p0 = __expf(g0 - m), p1 = __expf(g1 - m);
    const float p2 = (t == 0) ? __expf(g2 - m) : 0.0f;
    float s = p0 + p1 + p2;
    #pragma unroll
    for (int off = 32; off > 0; off >>= 1) s += __shfl_xor(s, off);
    __syncthreads();
    if (lane == 0) s_red[4 + wid] = s;
    __syncthreads();
    s = s_red[4] + s_red[5] + s_red[6] + s_red[7];
    const float inv = 1.0f / s;
    float* Ap = A + (size_t)bh * NF_;
    Ap[t] = p0 * inv;
    Ap[t + 256] = p1 * inv;
    if (t == 0) Ap[512] = p2 * inv;
}

// Kernel 3: block = one (b,h) x 2 e-channels. Stage V at bitrev positions,
// DIT fwd -> natural X; Hermitian manipulation in natural order (conflict-free);
// DIF inverse (natural in -> bitrev out); write Out[l=brev10(pos)].
__global__ __launch_bounds__(256) void k_vfft(const float* __restrict__ V,
                                              const float* __restrict__ A,
                                              float* __restrict__ Out) {
    __shared__ float2 s_z[1024];
    __shared__ float2 s_w[1024];
    __shared__ float2 s_tw[1024];
    __shared__ float s_A[NF_];

    const int t = threadIdx.x;
    const int bid = blockIdx.x;
    const int bh = bid >> 5, ep = bid & 31;
    const int b = bh >> 3, h = bh & 7;
    const int e0 = ep * 2;

    fill_tw(s_tw, t);
    for (int kk = t; kk < NF_; kk += 256) s_A[kk] = A[(size_t)bh * NF_ + kk];
    #pragma unroll
    for (int jj = 0; jj < 4; ++jj) {
        const int s = jj * 256 + t;
        const float* vp = V + (((size_t)b * L_ + s) * H_ + h) * E_ + e0;
        s_z[brev10(s)] = make_float2(vp[0], vp[1]);
    }
    __syncthreads();

    fft_dit(s_z, s_tw, t, -1.0f);   // natural-order X

    #pragma unroll
    for (int jj = 0; jj < 4; ++jj) {
        const int k = jj * 256 + t;
        const int m = (k <= 512) ? k : (N_ - k);
        const float sgn = (k <= 512) ? 1.0f : -1.0f;
        const int mp = (N_ - m) & (N_ - 1);
        const float2 X1 = s_z[m];
        const float2 X2 = s_z[mp];
        const float reV1 = 0.5f * (X1.x + X2.x);
        const float imV1 = 0.5f * (X1.y - X2.y);
        const float reV2 = 0.5f * (X1.y + X2.y);
        const float imV2 = 0.5f * (X2.x - X1.x);
        const float a = s_A[m];
        s_w[k] = make_float2(a * reV1 - sgn * imV2, sgn * imV1 + a * reV2);
    }
    __syncthreads();

    fft_dif(s_w, s_tw, t, +1.0f);   // unnormalized inverse, bitrev output

    const float invN = 1.0f / (float)N_;
    #pragma unroll
    for (int jj = 0; jj < 4; ++jj) {
        const int p = jj * 256 + t;
        const int l = brev10(p);
        const size_t o = (((size_t)b * L_ + l) * E_ + e0) * H_ + h;
        Out[o] = s_w[p].x * invN;        // e0   -> Re
        Out[o + H_] = s_w[p].y * invN;   // e0+1 -> Im
    }
}

extern "C" void kernel_launch(void* const* d_in, const int* in_sizes, int n_in,
                              void* d_out, int out_size, void* d_ws, size_t ws_size,
                              hipStream_t stream) {
    const float* Q = (const float*)d_in[0];
    const float* K = (const float*)d_in[1];
    const float* V = (const float*)d_in[2];
    float* out = (float*)d_out;

    float* ws = (float*)d_ws;
    float* qninv = ws;                       // B*L*H
    float* kninv = qninv + B_ * L_ * H_;     // B*L*H
    float* G     = kninv + B_ * L_ * H_;     // B*H*NF
    float* A     = G + B_ * H_ * NF_;        // B*H*NF

    hipMemsetAsync(G, 0, (size_t)B_ * H_ * NF_ * sizeof(float), stream);
    k_norms<<<(2 * B_ * L_ * H_ + 255) / 256, 256, 0, stream>>>(Q, K, qninv, kninv);
    k_qkfft<<<B_ * H_ * (L_ / 16), 256, 0, stream>>>(Q, K, qninv, kninv, G);
    k_softA<<<B_ * H_, 256, 0, stream>>>(G, A);
    k_vfft<<<B_ * H_ * (E_ / 2), 256, 0, stream>>>(V, A, out);
}

// Round 7
// 166.826 us; speedup vs baseline: 4.1147x; 1.7061x over previous
//
#include <hip/hip_runtime.h>
#include <hip/hip_bf16.h>
#include <math.h>

#define B_ 4
#define L_ 1024
#define H_ 8
#define E_ 64
#define N_ 1024
#define NF_ 513            // rfft bins for N=1024
#define SCALE_ 0.125f      // 1/sqrt(E)
#define HE_ (H_ * E_)

typedef _Float16 f16x8 __attribute__((ext_vector_type(8)));
typedef float f32x4 __attribute__((ext_vector_type(4)));

__device__ __forceinline__ int brev10(int x) {
    return (int)(__brev((unsigned)x) >> 22);
}

// Compact per-stage twiddles: stage with half-span S=2^ls stores its S entries
// at offset S-1, entry pos = (cos, sin)(pi*pos/S). Reads are consecutive or
// broadcast -> conflict-free. 1023 entries total.
__device__ __forceinline__ void fill_tw(float2* tw, int t) {
    for (int i = t; i < 1023; i += 256) {
        const int v = i + 1;
        const int ls = 31 - __clz(v);
        const int S = 1 << ls;
        float sv, cv;
        sincosf(3.14159265358979323846f * (float)(v - S) / (float)S, &sv, &cv);
        tw[i] = make_float2(cv, sv);
    }
}

// Radix-2 DIT: bit-reversed input -> natural output. dir=-1 fwd, +1 inv (unnorm).
// 256 threads, 1024 points, interleaved float2. Ends with __syncthreads().
__device__ __forceinline__ void fft_dit(float2* z, const float2* tw, int t, float dir) {
    #pragma unroll
    for (int ls = 0; ls <= 9; ++ls) {
        const int S = 1 << ls;
        #pragma unroll
        for (int jj = 0; jj < 2; ++jj) {
            const int j = t + jj * 256;
            const int pos = j & (S - 1);
            const int i1 = ((j >> ls) << (ls + 1)) + pos;
            const int i2 = i1 + S;
            const float2 w = tw[S - 1 + pos];
            const float wr = w.x, wi = dir * w.y;
            const float2 u = z[i1], v = z[i2];
            const float tr = v.x * wr - v.y * wi;
            const float ti = v.x * wi + v.y * wr;
            z[i1] = make_float2(u.x + tr, u.y + ti);
            z[i2] = make_float2(u.x - tr, u.y - ti);
        }
        __syncthreads();
    }
}

// Radix-2 DIF: natural input -> bit-reversed output. dir=-1 fwd, +1 inv (unnorm).
__device__ __forceinline__ void fft_dif(float2* z, const float2* tw, int t, float dir) {
    #pragma unroll
    for (int ls = 9; ls >= 0; --ls) {
        const int S = 1 << ls;
        #pragma unroll
        for (int jj = 0; jj < 2; ++jj) {
            const int j = t + jj * 256;
            const int pos = j & (S - 1);
            const int i1 = ((j >> ls) << (ls + 1)) + pos;
            const int i2 = i1 + S;
            const float2 w = tw[S - 1 + pos];
            const float wr = w.x, wi = dir * w.y;
            const float2 u = z[i1], v = z[i2];
            z[i1] = make_float2(u.x + v.x, u.y + v.y);
            const float dr = u.x - v.x, di = u.y - v.y;
            z[i2] = make_float2(dr * wr - di * wi, dr * wi + di * wr);
        }
        __syncthreads();
    }
}

// Kernel 0: qninv for Q rows; K rows -> unit-normalized f16 (Kh).
__global__ __launch_bounds__(256) void k_prep(const float* __restrict__ Q,
                                              const float* __restrict__ K,
                                              float* __restrict__ qninv,
                                              _Float16* __restrict__ Kh) {
    const int n = B_ * L_ * H_;
    const int i = blockIdx.x * 256 + threadIdx.x;
    if (i >= 2 * n) return;
    const float* p = (i < n) ? (Q + (size_t)i * E_) : (K + (size_t)(i - n) * E_);
    float ss = 0.0f;
    #pragma unroll
    for (int j = 0; j < 16; ++j) {
        const float4 v = *(const float4*)(p + j * 4);
        ss += v.x * v.x + v.y * v.y + v.z * v.z + v.w * v.w;
    }
    const float r = rsqrtf(ss);
    if (i < n) {
        qninv[i] = r;
    } else {
        _Float16* out = Kh + (size_t)(i - n) * E_;
        #pragma unroll
        for (int e = 0; e < E_; e += 8) {
            const float4 x = *(const float4*)(p + e);
            const float4 y = *(const float4*)(p + e + 4);
            f16x8 o;
            o[0] = (_Float16)(x.x * r); o[1] = (_Float16)(x.y * r);
            o[2] = (_Float16)(x.z * r); o[3] = (_Float16)(x.w * r);
            o[4] = (_Float16)(y.x * r); o[5] = (_Float16)(y.y * r);
            o[6] = (_Float16)(y.z * r); o[7] = (_Float16)(y.w * r);
            *(f16x8*)(out + e) = o;
        }
    }
}

// Kernel 1: block = one (b,h) x 16 q-rows. QK^T via mfma_f32_16x16x32_f16:
// M=16 q-rows, N=1024 FFT slots (slot j loads K row brev10(j), so the DIT
// input write stays linear/conflict-free), K=64 (2 MFMA k-steps).
// C/D layout (HW-verified): col=lane&15 (slot-in-tile), row=(lane>>4)*4+reg
// (q-row). Pair p (rows 2p,2p+1) = adjacent regs of lane group g==p>>1.
// A/B k-lane-mapping uncertainty is a consistent permutation of the
// summation axis (same mapping both operands) -> dot invariant.
__global__ __attribute__((amdgpu_flat_work_group_size(256, 256), amdgpu_waves_per_eu(2, 4)))
void k_qkfft(const float* __restrict__ Q,
             const _Float16* __restrict__ Kh,
             const float* __restrict__ qninv,
             float* __restrict__ G) {
    __shared__ float2 s_z[1024];    // 8 KB FFT buffer (interleaved)
    __shared__ float2 s_tw[1024];   // 8 KB compact twiddles
    __shared__ float s_acc[NF_];
    __shared__ float s_red[16];

    const int t = threadIdx.x;
    const int bid = blockIdx.x;
    const int bh = bid >> 6;        // consecutive blocks share (b,h) -> L2 reuse of Kh
    const int chunk = bid & 63;
    const int b = bh >> 3, h = bh & 7;
    const int l0 = chunk * 16;

    const int c = t & 15;           // A-row / B-col within 16-tile
    const int g = (t >> 4) & 3;     // k-group of the fragment
    const int w = t >> 6;           // wave id (slots [w*256, w*256+256))

    fill_tw(s_tw, t);
    for (int kk = t; kk < NF_; kk += 256) s_acc[kk] = 0.0f;
    __syncthreads();

    // ---- A fragments: q-row (l0+c), normalized, f16, on the fly ----
    const float qn = qninv[((size_t)b * L_ + l0 + c) * H_ + h];
    const float* qrow = Q + (((size_t)b * L_ + l0 + c) * H_ + h) * E_;
    f16x8 af0, af1;
    {
        const float4 x0 = *(const float4*)(qrow + g * 8);
        const float4 y0 = *(const float4*)(qrow + g * 8 + 4);
        af0[0] = (_Float16)(x0.x * qn); af0[1] = (_Float16)(x0.y * qn);
        af0[2] = (_Float16)(x0.z * qn); af0[3] = (_Float16)(x0.w * qn);
        af0[4] = (_Float16)(y0.x * qn); af0[5] = (_Float16)(y0.y * qn);
        af0[6] = (_Float16)(y0.z * qn); af0[7] = (_Float16)(y0.w * qn);
        const float4 x1 = *(const float4*)(qrow + 32 + g * 8);
        const float4 y1 = *(const float4*)(qrow + 32 + g * 8 + 4);
        af1[0] = (_Float16)(x1.x * qn); af1[1] = (_Float16)(x1.y * qn);
        af1[2] = (_Float16)(x1.z * qn); af1[3] = (_Float16)(x1.w * qn);
        af1[4] = (_Float16)(y1.x * qn); af1[5] = (_Float16)(y1.y * qn);
        af1[6] = (_Float16)(y1.z * qn); af1[7] = (_Float16)(y1.w * qn);
    }

    // ---- B fragments + MFMA: 16 N-tiles, 2 k-steps each ----
    f32x4 acc[16];
    #pragma unroll
    for (int n = 0; n < 16; ++n) acc[n] = (f32x4){0.0f, 0.0f, 0.0f, 0.0f};

    #pragma unroll
    for (int n = 0; n < 16; ++n) {
        const int j = w * 256 + n * 16 + c;
        const int s = brev10(j);
        const f16x8* bp = (const f16x8*)(Kh + (((size_t)b * L_ + s) * H_ + h) * E_);
        const f16x8 b0 = bp[g];         // e = g*8 .. g*8+7
        const f16x8 b1 = bp[4 + g];     // e = 32 + g*8 ..
        acc[n] = __builtin_amdgcn_mfma_f32_16x16x32_f16(af0, b0, acc[n], 0, 0, 0);
        acc[n] = __builtin_amdgcn_mfma_f32_16x16x32_f16(af1, b1, acc[n], 0, 0, 0);
        if ((n & 3) == 3) __builtin_amdgcn_sched_barrier(0);  // fence load hoisting
    }

    // sim = exp(cos) in place
    #pragma unroll
    for (int n = 0; n < 16; ++n) {
        #pragma unroll
        for (int r = 0; r < 4; ++r) acc[n][r] = __expf(acc[n][r]);
    }

    // ---- 8 packed pair-FFTs + per-row softmax + accumulate ----
    #pragma unroll
    for (int p = 0; p < 8; ++p) {
        __syncthreads();   // prior extraction/s_red reads complete
        if (g == (p >> 1)) {
            const int e0 = (2 * p) & 3;
            #pragma unroll
            for (int n = 0; n < 16; ++n)
                s_z[w * 256 + n * 16 + c] = make_float2(acc[n][e0], acc[n][e0 + 1]);
        }
        __syncthreads();
        fft_dit(s_z, s_tw, t, -1.0f);   // natural-order X

        // Re F_A[k] = (ReX[k]+ReX[N-k])/2 ; Re F_B[k] = (ImX[k]+ImX[N-k])/2
        const float2 X0  = s_z[t];
        const float2 X0n = s_z[(N_ - t) & (N_ - 1)];
        const float2 X1  = s_z[t + 256];
        const float2 X1n = s_z[768 - t];
        const float a0 = SCALE_ * 0.5f * (X0.x + X0n.x);
        const float b0 = SCALE_ * 0.5f * (X0.y + X0n.y);
        const float a1 = SCALE_ * 0.5f * (X1.x + X1n.x);
        const float b1 = SCALE_ * 0.5f * (X1.y + X1n.y);
        float a2 = -1e30f, b2 = -1e30f;
        if (t == 0) {
            const float2 Xm = s_z[512];
            a2 = SCALE_ * Xm.x;
            b2 = SCALE_ * Xm.y;
        }

        float mA = fmaxf(fmaxf(a0, a1), a2);
        float mB = fmaxf(fmaxf(b0, b1), b2);
        #pragma unroll
        for (int off = 32; off > 0; off >>= 1) {
            mA = fmaxf(mA, __shfl_xor(mA, off));
            mB = fmaxf(mB, __shfl_xor(mB, off));
        }
        const int lane = t & 63, wid = t >> 6;
        if (lane == 0) { s_red[wid] = mA; s_red[4 + wid] = mB; }
        __syncthreads();
        mA = fmaxf(fmaxf(s_red[0], s_red[1]), fmaxf(s_red[2], s_red[3]));
        mB = fmaxf(fmaxf(s_red[4], s_red[5]), fmaxf(s_red[6], s_red[7]));

        const float pA0 = __expf(a0 - mA), pA1 = __expf(a1 - mA);
        const float pB0 = __expf(b0 - mB), pB1 = __expf(b1 - mB);
        const float pA2 = (t == 0) ? __expf(a2 - mA) : 0.0f;
        const float pB2 = (t == 0) ? __expf(b2 - mB) : 0.0f;
        float sA = pA0 + pA1 + pA2, sB = pB0 + pB1 + pB2;
        #pragma unroll
        for (int off = 32; off > 0; off >>= 1) {
            sA += __shfl_xor(sA, off);
            sB += __shfl_xor(sB, off);
        }
        __syncthreads();
        if (lane == 0) { s_red[8 + wid] = sA; s_red[12 + wid] = sB; }
        __syncthreads();
        sA = s_red[8] + s_red[9] + s_red[10] + s_red[11];
        sB = s_red[12] + s_red[13] + s_red[14] + s_red[15];
        const float iA = 1.0f / sA, iB = 1.0f / sB;

        s_acc[t]       += pA0 * iA + pB0 * iB;
        s_acc[t + 256] += pA1 * iA + pB1 * iB;
        if (t == 0) s_acc[512] += pA2 * iA + pB2 * iB;
    }
    __syncthreads();

    float* Gp = G + (size_t)bh * NF_;
    for (int kk = t; kk < NF_; kk += 256) atomicAdd(&Gp[kk], s_acc[kk]);
}

// Kernel 2: A[b,h,:] = softmax(G[b,h,:]) over 513 bins.
__global__ __launch_bounds__(256) void k_softA(const float* __restrict__ G,
                                               float* __restrict__ A) {
    __shared__ float s_red[16];
    const int bh = blockIdx.x, t = threadIdx.x;
    const float* Gp = G + (size_t)bh * NF_;
    const float g0 = Gp[t];
    const float g1 = Gp[t + 256];
    const float g2 = (t == 0) ? Gp[512] : -1e30f;
    float m = fmaxf(fmaxf(g0, g1), g2);
    #pragma unroll
    for (int off = 32; off > 0; off >>= 1) m = fmaxf(m, __shfl_xor(m, off));
    const int lane = t & 63, wid = t >> 6;
    if (lane == 0) s_red[wid] = m;
    __syncthreads();
    m = fmaxf(fmaxf(s_red[0], s_red[1]), fmaxf(s_red[2], s_red[3]));
    const float p0 = __expf(g0 - m), p1 = __expf(g1 - m);
    const float p2 = (t == 0) ? __expf(g2 - m) : 0.0f;
    float s = p0 + p1 + p2;
    #pragma unroll
    for (int off = 32; off > 0; off >>= 1) s += __shfl_xor(s, off);
    __syncthreads();
    if (lane == 0) s_red[4 + wid] = s;
    __syncthreads();
    s = s_red[4] + s_red[5] + s_red[6] + s_red[7];
    const float inv = 1.0f / s;
    float* Ap = A + (size_t)bh * NF_;
    Ap[t] = p0 * inv;
    Ap[t + 256] = p1 * inv;
    if (t == 0) Ap[512] = p2 * inv;
}

// Kernel 3: block = one (b,h) x 2 e-channels. Stage V at bitrev positions,
// DIT fwd -> natural X; Hermitian manipulation in natural order (conflict-free);
// DIF inverse (natural in -> bitrev out); write Out[l=brev10(pos)].
__global__ __launch_bounds__(256) void k_vfft(const float* __restrict__ V,
                                              const float* __restrict__ A,
                                              float* __restrict__ Out) {
    __shared__ float2 s_z[1024];
    __shared__ float2 s_w[1024];
    __shared__ float2 s_tw[1024];
    __shared__ float s_A[NF_];

    const int t = threadIdx.x;
    const int bid = blockIdx.x;
    const int bh = bid >> 5, ep = bid & 31;
    const int b = bh >> 3, h = bh & 7;
    const int e0 = ep * 2;

    fill_tw(s_tw, t);
    for (int kk = t; kk < NF_; kk += 256) s_A[kk] = A[(size_t)bh * NF_ + kk];
    #pragma unroll
    for (int jj = 0; jj < 4; ++jj) {
        const int s = jj * 256 + t;
        const float* vp = V + (((size_t)b * L_ + s) * H_ + h) * E_ + e0;
        s_z[brev10(s)] = make_float2(vp[0], vp[1]);
    }
    __syncthreads();

    fft_dit(s_z, s_tw, t, -1.0f);   // natural-order X

    #pragma unroll
    for (int jj = 0; jj < 4; ++jj) {
        const int k = jj * 256 + t;
        const int m = (k <= 512) ? k : (N_ - k);
        const float sgn = (k <= 512) ? 1.0f : -1.0f;
        const int mp = (N_ - m) & (N_ - 1);
        const float2 X1 = s_z[m];
        const float2 X2 = s_z[mp];
        const float reV1 = 0.5f * (X1.x + X2.x);
        const float imV1 = 0.5f * (X1.y - X2.y);
        const float reV2 = 0.5f * (X1.y + X2.y);
        const float imV2 = 0.5f * (X2.x - X1.x);
        const float a = s_A[m];
        s_w[k] = make_float2(a * reV1 - sgn * imV2, sgn * imV1 + a * reV2);
    }
    __syncthreads();

    fft_dif(s_w, s_tw, t, +1.0f);   // unnormalized inverse, bitrev output

    const float invN = 1.0f / (float)N_;
    #pragma unroll
    for (int jj = 0; jj < 4; ++jj) {
        const int p = jj * 256 + t;
        const int l = brev10(p);
        const size_t o = (((size_t)b * L_ + l) * E_ + e0) * H_ + h;
        Out[o] = s_w[p].x * invN;        // e0   -> Re
        Out[o + H_] = s_w[p].y * invN;   // e0+1 -> Im
    }
}

extern "C" void kernel_launch(void* const* d_in, const int* in_sizes, int n_in,
                              void* d_out, int out_size, void* d_ws, size_t ws_size,
                              hipStream_t stream) {
    const float* Q = (const float*)d_in[0];
    const float* K = (const float*)d_in[1];
    const float* V = (const float*)d_in[2];
    float* out = (float*)d_out;

    float* ws = (float*)d_ws;
    float* qninv   = ws;                                   // B*L*H floats
    _Float16* Kh   = (_Float16*)(ws + B_ * L_ * H_);       // B*L*H*E halves (4 MB)
    float* G       = ws + B_ * L_ * H_ + (B_ * L_ * H_ * E_) / 2;
    float* A       = G + B_ * H_ * NF_;

    hipMemsetAsync(G, 0, (size_t)B_ * H_ * NF_ * sizeof(float), stream);
    k_prep<<<(2 * B_ * L_ * H_ + 255) / 256, 256, 0, stream>>>(Q, K, qninv, Kh);
    k_qkfft<<<B_ * H_ * (L_ / 16), 256, 0, stream>>>(Q, Kh, qninv, G);
    k_softA<<<B_ * H_, 256, 0, stream>>>(G, A);
    k_vfft<<<B_ * H_ * (E_ / 2), 256, 0, stream>>>(V, A, out);
}

// Round 8
// 141.273 us; speedup vs baseline: 4.8590x; 1.1809x over previous
//
#include <hip/hip_runtime.h>
#include <hip/hip_bf16.h>
#include <math.h>

#define B_ 4
#define L_ 1024
#define H_ 8
#define E_ 64
#define N_ 1024
#define NF_ 513            // rfft bins for N=1024
#define SCALE_ 0.125f      // 1/sqrt(E)
#define HE_ (H_ * E_)

typedef _Float16 f16x8 __attribute__((ext_vector_type(8)));
typedef float f32x4 __attribute__((ext_vector_type(4)));

// base-4 digit reversal of a 10-bit index (5 digits); involution.
__device__ __forceinline__ int dr4(int x) {
    const int r = (int)(__brev((unsigned)x) >> 22);   // bit-reverse 10 bits
    return ((r & 0x155) << 1) | ((r >> 1) & 0x155);   // swap adjacent bits
}

// w = (cos, sin); multiply v by exp(dir*i*theta) where tw stores theta>0 entries.
__device__ __forceinline__ float2 cmulw(float2 v, float2 w, float dir) {
    const float wi = dir * w.y;
    return make_float2(v.x * w.x - v.y * wi, v.x * wi + v.y * w.x);
}

// radix-4 combine: y_q = sum_m x_m * W4^{q*m}, W4 = exp(dir*i*pi/2).
__device__ __forceinline__ void r4c(const float2 x0, const float2 x1,
                                    const float2 x2, const float2 x3,
                                    const float dir,
                                    float2& y0, float2& y1, float2& y2, float2& y3) {
    const float ax = x0.x + x2.x, ay = x0.y + x2.y;
    const float bx = x0.x - x2.x, by = x0.y - x2.y;
    const float cx = x1.x + x3.x, cy = x1.y + x3.y;
    const float dx = x1.x - x3.x, dy = x1.y - x3.y;
    y0 = make_float2(ax + cx, ay + cy);
    y2 = make_float2(ax - cx, ay - cy);
    y1 = make_float2(bx - dir * dy, by + dir * dx);
    y3 = make_float2(bx + dir * dy, by - dir * dx);
}

// Full twiddle table: tw[k] = (cos, sin)(2*pi*k/1024).
__device__ __forceinline__ void fill_tw(float2* tw, int t) {
    for (int i = t; i < 1024; i += 256) {
        float sv, cv;
        sincosf(6.283185307179586f * (float)i / 1024.0f, &sv, &cv);
        tw[i] = make_float2(cv, sv);
    }
}

// Radix-4 DIT: digit-reversed input -> natural output. 5 stages, 5 barriers.
__device__ __forceinline__ void fft_dit4(float2* z, const float2* tw, int t, float dir) {
    {   // stage 0 (span 1): no twiddles, float4 IO
        float4* z4 = (float4*)z;
        const float4 p01 = z4[2 * t], p23 = z4[2 * t + 1];
        float2 y0, y1, y2, y3;
        r4c(make_float2(p01.x, p01.y), make_float2(p01.z, p01.w),
            make_float2(p23.x, p23.y), make_float2(p23.z, p23.w), dir, y0, y1, y2, y3);
        z4[2 * t]     = make_float4(y0.x, y0.y, y1.x, y1.y);
        z4[2 * t + 1] = make_float4(y2.x, y2.y, y3.x, y3.y);
        __syncthreads();
    }
    #pragma unroll
    for (int st = 1; st < 5; ++st) {
        const int l2q = 2 * st, qs = 1 << l2q;
        const int pos = t & (qs - 1);
        const int base = ((t >> l2q) << (l2q + 2)) + pos;
        const int step = 1 << (8 - l2q);
        const float2 w1 = tw[pos * step], w2 = tw[2 * pos * step], w3 = tw[3 * pos * step];
        const float2 x0 = z[base];
        const float2 x1 = cmulw(z[base + qs], w1, dir);
        const float2 x2 = cmulw(z[base + 2 * qs], w2, dir);
        const float2 x3 = cmulw(z[base + 3 * qs], w3, dir);
        float2 y0, y1, y2, y3;
        r4c(x0, x1, x2, x3, dir, y0, y1, y2, y3);
        z[base] = y0; z[base + qs] = y1; z[base + 2 * qs] = y2; z[base + 3 * qs] = y3;
        __syncthreads();
    }
}

// Radix-4 DIF: natural input -> digit-reversed output. 5 stages, 5 barriers.
__device__ __forceinline__ void fft_dif4(float2* z, const float2* tw, int t, float dir) {
    #pragma unroll
    for (int st = 4; st >= 1; --st) {
        const int l2q = 2 * st, qs = 1 << l2q;
        const int pos = t & (qs - 1);
        const int base = ((t >> l2q) << (l2q + 2)) + pos;
        const int step = 1 << (8 - l2q);
        const float2 x0 = z[base], x1 = z[base + qs], x2 = z[base + 2 * qs], x3 = z[base + 3 * qs];
        float2 s0, s1, s2, s3;
        r4c(x0, x1, x2, x3, dir, s0, s1, s2, s3);
        const float2 w1 = tw[pos * step], w2 = tw[2 * pos * step], w3 = tw[3 * pos * step];
        z[base] = s0;
        z[base + qs]     = cmulw(s1, w1, dir);
        z[base + 2 * qs] = cmulw(s2, w2, dir);
        z[base + 3 * qs] = cmulw(s3, w3, dir);
        __syncthreads();
    }
    {   // stage 0
        float4* z4 = (float4*)z;
        const float4 p01 = z4[2 * t], p23 = z4[2 * t + 1];
        float2 s0, s1, s2, s3;
        r4c(make_float2(p01.x, p01.y), make_float2(p01.z, p01.w),
            make_float2(p23.x, p23.y), make_float2(p23.z, p23.w), dir, s0, s1, s2, s3);
        z4[2 * t]     = make_float4(s0.x, s0.y, s1.x, s1.y);
        z4[2 * t + 1] = make_float4(s2.x, s2.y, s3.x, s3.y);
        __syncthreads();
    }
}

// Kernel 0: qninv for Q rows; K rows -> unit-normalized f16 (Kh).
__global__ __launch_bounds__(256) void k_prep(const float* __restrict__ Q,
                                              const float* __restrict__ K,
                                              float* __restrict__ qninv,
                                              _Float16* __restrict__ Kh) {
    const int n = B_ * L_ * H_;
    const int i = blockIdx.x * 256 + threadIdx.x;
    if (i >= 2 * n) return;
    const float* p = (i < n) ? (Q + (size_t)i * E_) : (K + (size_t)(i - n) * E_);
    float ss = 0.0f;
    #pragma unroll
    for (int j = 0; j < 16; ++j) {
        const float4 v = *(const float4*)(p + j * 4);
        ss += v.x * v.x + v.y * v.y + v.z * v.z + v.w * v.w;
    }
    const float r = rsqrtf(ss);
    if (i < n) {
        qninv[i] = r;
    } else {
        _Float16* out = Kh + (size_t)(i - n) * E_;
        #pragma unroll
        for (int e = 0; e < E_; e += 8) {
            const float4 x = *(const float4*)(p + e);
            const float4 y = *(const float4*)(p + e + 4);
            f16x8 o;
            o[0] = (_Float16)(x.x * r); o[1] = (_Float16)(x.y * r);
            o[2] = (_Float16)(x.z * r); o[3] = (_Float16)(x.w * r);
            o[4] = (_Float16)(y.x * r); o[5] = (_Float16)(y.y * r);
            o[6] = (_Float16)(y.z * r); o[7] = (_Float16)(y.w * r);
            *(f16x8*)(out + e) = o;
        }
    }
}

// Kernel 1: block = one (b,h) x 16 q-rows. QK^T via mfma_f32_16x16x32_f16
// (slot j loads K row dr4(j) so the radix-4 DIT input store is linear).
// FFT phase: 4 rounds, each with TWO concurrent pair-FFTs (z0: rows 4r,4r+1;
// z1: rows 4r+2,4r+3 — both owned by lane group g==r) -> radix-4 dual stages
// (5 barriers) + fused 4-row softmax (2 barriers). ~34 barriers/block vs 114
// in the radix-2 single-FFT version (round-7 profile: VALUBusy 27%, Occ 30%,
// nothing saturated = barrier-serialization).
__global__ __attribute__((amdgpu_flat_work_group_size(256, 256), amdgpu_waves_per_eu(2, 4)))
void k_qkfft(const float* __restrict__ Q,
             const _Float16* __restrict__ Kh,
             const float* __restrict__ qninv,
             float* __restrict__ G) {
    __shared__ __align__(16) float2 s_z0[1024];   // 8 KB
    __shared__ __align__(16) float2 s_z1[1024];   // 8 KB
    __shared__ float2 s_tw[1024];                 // 8 KB
    __shared__ float s_acc[NF_];
    __shared__ float s_red[32];

    const int t = threadIdx.x;
    const int bid = blockIdx.x;
    const int bh = bid >> 6;        // consecutive blocks share (b,h) -> L2 reuse of Kh
    const int chunk = bid & 63;
    const int b = bh >> 3, h = bh & 7;
    const int l0 = chunk * 16;

    const int c = t & 15;           // A-row / B-col within 16-tile
    const int g = (t >> 4) & 3;     // k-group of the fragment / acc row-group
    const int w = t >> 6;           // wave id (slots [w*256, w*256+256))

    fill_tw(s_tw, t);
    for (int kk = t; kk < NF_; kk += 256) s_acc[kk] = 0.0f;
    __syncthreads();

    // ---- A fragments: q-row (l0+c), normalized, f16, on the fly ----
    const float qn = qninv[((size_t)b * L_ + l0 + c) * H_ + h];
    const float* qrow = Q + (((size_t)b * L_ + l0 + c) * H_ + h) * E_;
    f16x8 af0, af1;
    {
        const float4 x0 = *(const float4*)(qrow + g * 8);
        const float4 y0 = *(const float4*)(qrow + g * 8 + 4);
        af0[0] = (_Float16)(x0.x * qn); af0[1] = (_Float16)(x0.y * qn);
        af0[2] = (_Float16)(x0.z * qn); af0[3] = (_Float16)(x0.w * qn);
        af0[4] = (_Float16)(y0.x * qn); af0[5] = (_Float16)(y0.y * qn);
        af0[6] = (_Float16)(y0.z * qn); af0[7] = (_Float16)(y0.w * qn);
        const float4 x1 = *(const float4*)(qrow + 32 + g * 8);
        const float4 y1 = *(const float4*)(qrow + 32 + g * 8 + 4);
        af1[0] = (_Float16)(x1.x * qn); af1[1] = (_Float16)(x1.y * qn);
        af1[2] = (_Float16)(x1.z * qn); af1[3] = (_Float16)(x1.w * qn);
        af1[4] = (_Float16)(y1.x * qn); af1[5] = (_Float16)(y1.y * qn);
        af1[6] = (_Float16)(y1.z * qn); af1[7] = (_Float16)(y1.w * qn);
    }

    // ---- B fragments + MFMA: 16 N-tiles, 2 k-steps each ----
    f32x4 acc[16];
    #pragma unroll
    for (int n = 0; n < 16; ++n) acc[n] = (f32x4){0.0f, 0.0f, 0.0f, 0.0f};

    #pragma unroll
    for (int n = 0; n < 16; ++n) {
        const int j = w * 256 + n * 16 + c;
        const int s = dr4(j);
        const f16x8* bp = (const f16x8*)(Kh + (((size_t)b * L_ + s) * H_ + h) * E_);
        const f16x8 b0 = bp[g];
        const f16x8 b1 = bp[4 + g];
        acc[n] = __builtin_amdgcn_mfma_f32_16x16x32_f16(af0, b0, acc[n], 0, 0, 0);
        acc[n] = __builtin_amdgcn_mfma_f32_16x16x32_f16(af1, b1, acc[n], 0, 0, 0);
        if ((n & 3) == 3) __builtin_amdgcn_sched_barrier(0);  // fence load hoisting
    }

    // sim = exp(cos) in place
    #pragma unroll
    for (int n = 0; n < 16; ++n) {
        #pragma unroll
        for (int r = 0; r < 4; ++r) acc[n][r] = __expf(acc[n][r]);
    }

    const int lane = t & 63, wid = t >> 6;
    const float dir = -1.0f;

    // ---- 4 rounds x (2 concurrent pair-FFTs + fused 4-row softmax) ----
    #pragma unroll
    for (int rr = 0; rr < 4; ++rr) {
        if (g == rr) {
            #pragma unroll
            for (int n = 0; n < 16; ++n) {
                const int slot = w * 256 + n * 16 + c;
                s_z0[slot] = make_float2(acc[n][0], acc[n][1]);
                s_z1[slot] = make_float2(acc[n][2], acc[n][3]);
            }
        }
        __syncthreads();

        // dual radix-4 DIT (digit-reversed in -> natural out), 5 barriers
        {   // stage 0
            float4* z04 = (float4*)s_z0;
            float4* z14 = (float4*)s_z1;
            const float4 a01 = z04[2 * t], a23 = z04[2 * t + 1];
            const float4 b01 = z14[2 * t], b23 = z14[2 * t + 1];
            float2 ay0, ay1, ay2, ay3, by0, by1, by2, by3;
            r4c(make_float2(a01.x, a01.y), make_float2(a01.z, a01.w),
                make_float2(a23.x, a23.y), make_float2(a23.z, a23.w), dir, ay0, ay1, ay2, ay3);
            r4c(make_float2(b01.x, b01.y), make_float2(b01.z, b01.w),
                make_float2(b23.x, b23.y), make_float2(b23.z, b23.w), dir, by0, by1, by2, by3);
            z04[2 * t]     = make_float4(ay0.x, ay0.y, ay1.x, ay1.y);
            z04[2 * t + 1] = make_float4(ay2.x, ay2.y, ay3.x, ay3.y);
            z14[2 * t]     = make_float4(by0.x, by0.y, by1.x, by1.y);
            z14[2 * t + 1] = make_float4(by2.x, by2.y, by3.x, by3.y);
            __syncthreads();
        }
        #pragma unroll
        for (int st = 1; st < 5; ++st) {
            const int l2q = 2 * st, qs = 1 << l2q;
            const int pos = t & (qs - 1);
            const int base = ((t >> l2q) << (l2q + 2)) + pos;
            const int step = 1 << (8 - l2q);
            const float2 w1 = s_tw[pos * step], w2 = s_tw[2 * pos * step], w3 = s_tw[3 * pos * step];
            const float2 a0 = s_z0[base];
            const float2 a1 = cmulw(s_z0[base + qs], w1, dir);
            const float2 a2 = cmulw(s_z0[base + 2 * qs], w2, dir);
            const float2 a3 = cmulw(s_z0[base + 3 * qs], w3, dir);
            const float2 b0 = s_z1[base];
            const float2 b1 = cmulw(s_z1[base + qs], w1, dir);
            const float2 b2 = cmulw(s_z1[base + 2 * qs], w2, dir);
            const float2 b3 = cmulw(s_z1[base + 3 * qs], w3, dir);
            float2 ay0, ay1, ay2, ay3, by0, by1, by2, by3;
            r4c(a0, a1, a2, a3, dir, ay0, ay1, ay2, ay3);
            r4c(b0, b1, b2, b3, dir, by0, by1, by2, by3);
            s_z0[base] = ay0; s_z0[base + qs] = ay1; s_z0[base + 2 * qs] = ay2; s_z0[base + 3 * qs] = ay3;
            s_z1[base] = by0; s_z1[base + qs] = by1; s_z1[base + 2 * qs] = by2; s_z1[base + 3 * qs] = by3;
            __syncthreads();
        }

        // extraction: 4 rows (z0.x, z0.y, z1.x, z1.y), bins t / t+256 (+512 @t0)
        const float2 XA0 = s_z0[t],      XA0n = s_z0[(N_ - t) & (N_ - 1)];
        const float2 XA1 = s_z0[t + 256], XA1n = s_z0[768 - t];
        const float2 XB0 = s_z1[t],      XB0n = s_z1[(N_ - t) & (N_ - 1)];
        const float2 XB1 = s_z1[t + 256], XB1n = s_z1[768 - t];
        float v[4][2], vm[4];
        v[0][0] = SCALE_ * 0.5f * (XA0.x + XA0n.x); v[0][1] = SCALE_ * 0.5f * (XA1.x + XA1n.x);
        v[1][0] = SCALE_ * 0.5f * (XA0.y + XA0n.y); v[1][1] = SCALE_ * 0.5f * (XA1.y + XA1n.y);
        v[2][0] = SCALE_ * 0.5f * (XB0.x + XB0n.x); v[2][1] = SCALE_ * 0.5f * (XB1.x + XB1n.x);
        v[3][0] = SCALE_ * 0.5f * (XB0.y + XB0n.y); v[3][1] = SCALE_ * 0.5f * (XB1.y + XB1n.y);
        if (t == 0) {
            const float2 ZA = s_z0[512], ZB = s_z1[512];
            vm[0] = SCALE_ * ZA.x; vm[1] = SCALE_ * ZA.y;
            vm[2] = SCALE_ * ZB.x; vm[3] = SCALE_ * ZB.y;
        } else {
            vm[0] = vm[1] = vm[2] = vm[3] = -1e30f;
        }

        float mx[4];
        #pragma unroll
        for (int q = 0; q < 4; ++q) mx[q] = fmaxf(fmaxf(v[q][0], v[q][1]), vm[q]);
        #pragma unroll
        for (int off = 32; off > 0; off >>= 1) {
            #pragma unroll
            for (int q = 0; q < 4; ++q) mx[q] = fmaxf(mx[q], __shfl_xor(mx[q], off));
        }
        if (lane == 0) {
            s_red[wid] = mx[0]; s_red[4 + wid] = mx[1];
            s_red[8 + wid] = mx[2]; s_red[12 + wid] = mx[3];
        }
        __syncthreads();
        #pragma unroll
        for (int q = 0; q < 4; ++q)
            mx[q] = fmaxf(fmaxf(s_red[4 * q], s_red[4 * q + 1]),
                          fmaxf(s_red[4 * q + 2], s_red[4 * q + 3]));

        float p[4][2], pm[4], sm[4];
        #pragma unroll
        for (int q = 0; q < 4; ++q) {
            p[q][0] = __expf(v[q][0] - mx[q]);
            p[q][1] = __expf(v[q][1] - mx[q]);
            pm[q] = (t == 0) ? __expf(vm[q] - mx[q]) : 0.0f;
            sm[q] = p[q][0] + p[q][1] + pm[q];
        }
        #pragma unroll
        for (int off = 32; off > 0; off >>= 1) {
            #pragma unroll
            for (int q = 0; q < 4; ++q) sm[q] += __shfl_xor(sm[q], off);
        }
        if (lane == 0) {
            s_red[16 + wid] = sm[0]; s_red[20 + wid] = sm[1];
            s_red[24 + wid] = sm[2]; s_red[28 + wid] = sm[3];
        }
        __syncthreads();
        #pragma unroll
        for (int q = 0; q < 4; ++q)
            sm[q] = 1.0f / (s_red[16 + 4 * q] + s_red[17 + 4 * q] +
                            s_red[18 + 4 * q] + s_red[19 + 4 * q]);

        s_acc[t]       += p[0][0] * sm[0] + p[1][0] * sm[1] + p[2][0] * sm[2] + p[3][0] * sm[3];
        s_acc[t + 256] += p[0][1] * sm[0] + p[1][1] * sm[1] + p[2][1] * sm[2] + p[3][1] * sm[3];
        if (t == 0)
            s_acc[512] += pm[0] * sm[0] + pm[1] * sm[1] + pm[2] * sm[2] + pm[3] * sm[3];
    }
    __syncthreads();

    float* Gp = G + (size_t)bh * NF_;
    for (int kk = t; kk < NF_; kk += 256) atomicAdd(&Gp[kk], s_acc[kk]);
}

// Kernel 2: A[b,h,:] = softmax(G[b,h,:]) over 513 bins.
__global__ __launch_bounds__(256) void k_softA(const float* __restrict__ G,
                                               float* __restrict__ A) {
    __shared__ float s_red[16];
    const int bh = blockIdx.x, t = threadIdx.x;
    const float* Gp = G + (size_t)bh * NF_;
    const float g0 = Gp[t];
    const float g1 = Gp[t + 256];
    const float g2 = (t == 0) ? Gp[512] : -1e30f;
    float m = fmaxf(fmaxf(g0, g1), g2);
    #pragma unroll
    for (int off = 32; off > 0; off >>= 1) m = fmaxf(m, __shfl_xor(m, off));
    const int lane = t & 63, wid = t >> 6;
    if (lane == 0) s_red[wid] = m;
    __syncthreads();
    m = fmaxf(fmaxf(s_red[0], s_red[1]), fmaxf(s_red[2], s_red[3]));
    const float p0 = __expf(g0 - m), p1 = __expf(g1 - m);
    const float p2 = (t == 0) ? __expf(g2 - m) : 0.0f;
    float s = p0 + p1 + p2;
    #pragma unroll
    for (int off = 32; off > 0; off >>= 1) s += __shfl_xor(s, off);
    __syncthreads();
    if (lane == 0) s_red[4 + wid] = s;
    __syncthreads();
    s = s_red[4] + s_red[5] + s_red[6] + s_red[7];
    const float inv = 1.0f / s;
    float* Ap = A + (size_t)bh * NF_;
    Ap[t] = p0 * inv;
    Ap[t + 256] = p1 * inv;
    if (t == 0) Ap[512] = p2 * inv;
}

// Kernel 3: block = one (b,h) x 2 e-channels. Stage V at dr4 positions,
// radix-4 DIT fwd -> natural X; Hermitian manipulation in natural order;
// radix-4 DIF inverse (natural -> digit-reversed); write Out[l=dr4(pos)].
__global__ __launch_bounds__(256) void k_vfft(const float* __restrict__ V,
                                              const float* __restrict__ A,
                                              float* __restrict__ Out) {
    __shared__ __align__(16) float2 s_z[1024];
    __shared__ __align__(16) float2 s_w[1024];
    __shared__ float2 s_tw[1024];
    __shared__ float s_A[NF_];

    const int t = threadIdx.x;
    const int bid = blockIdx.x;
    const int bh = bid >> 5, ep = bid & 31;
    const int b = bh >> 3, h = bh & 7;
    const int e0 = ep * 2;

    fill_tw(s_tw, t);
    for (int kk = t; kk < NF_; kk += 256) s_A[kk] = A[(size_t)bh * NF_ + kk];
    #pragma unroll
    for (int jj = 0; jj < 4; ++jj) {
        const int s = jj * 256 + t;
        const float* vp = V + (((size_t)b * L_ + s) * H_ + h) * E_ + e0;
        s_z[dr4(s)] = make_float2(vp[0], vp[1]);
    }
    __syncthreads();

    fft_dit4(s_z, s_tw, t, -1.0f);   // natural-order X

    #pragma unroll
    for (int jj = 0; jj < 4; ++jj) {
        const int k = jj * 256 + t;
        const int m = (k <= 512) ? k : (N_ - k);
        const float sgn = (k <= 512) ? 1.0f : -1.0f;
        const int mp = (N_ - m) & (N_ - 1);
        const float2 X1 = s_z[m];
        const float2 X2 = s_z[mp];
        const float reV1 = 0.5f * (X1.x + X2.x);
        const float imV1 = 0.5f * (X1.y - X2.y);
        const float reV2 = 0.5f * (X1.y + X2.y);
        const float imV2 = 0.5f * (X2.x - X1.x);
        const float a = s_A[m];
        s_w[k] = make_float2(a * reV1 - sgn * imV2, sgn * imV1 + a * reV2);
    }
    __syncthreads();

    fft_dif4(s_w, s_tw, t, +1.0f);   // unnormalized inverse, digit-reversed out

    const float invN = 1.0f / (float)N_;
    #pragma unroll
    for (int jj = 0; jj < 4; ++jj) {
        const int p = jj * 256 + t;
        const int l = dr4(p);
        const size_t o = (((size_t)b * L_ + l) * E_ + e0) * H_ + h;
        Out[o] = s_w[p].x * invN;        // e0   -> Re
        Out[o + H_] = s_w[p].y * invN;   // e0+1 -> Im
    }
}

extern "C" void kernel_launch(void* const* d_in, const int* in_sizes, int n_in,
                              void* d_out, int out_size, void* d_ws, size_t ws_size,
                              hipStream_t stream) {
    const float* Q = (const float*)d_in[0];
    const float* K = (const float*)d_in[1];
    const float* V = (const float*)d_in[2];
    float* out = (float*)d_out;

    float* ws = (float*)d_ws;
    float* qninv   = ws;                                   // B*L*H floats
    _Float16* Kh   = (_Float16*)(ws + B_ * L_ * H_);       // B*L*H*E halves (4 MB)
    float* G       = ws + B_ * L_ * H_ + (B_ * L_ * H_ * E_) / 2;
    float* A       = G + B_ * H_ * NF_;

    hipMemsetAsync(G, 0, (size_t)B_ * H_ * NF_ * sizeof(float), stream);
    k_prep<<<(2 * B_ * L_ * H_ + 255) / 256, 256, 0, stream>>>(Q, K, qninv, Kh);
    k_qkfft<<<B_ * H_ * (L_ / 16), 256, 0, stream>>>(Q, Kh, qninv, G);
    k_softA<<<B_ * H_, 256, 0, stream>>>(G, A);
    k_vfft<<<B_ * H_ * (E_ / 2), 256, 0, stream>>>(V, A, out);
}

// Round 9
// 119.094 us; speedup vs baseline: 5.7639x; 1.1862x over previous
//
#include <hip/hip_runtime.h>
#include <hip/hip_bf16.h>
#include <math.h>

#define B_ 4
#define L_ 1024
#define H_ 8
#define E_ 64
#define N_ 1024
#define NF_ 513            // rfft bins for N=1024
#define SCALE_ 0.125f      // 1/sqrt(E)
#define HE_ (H_ * E_)
#define ZP_ 1104           // padded float2 slots for 1024 points (PD(1023)=1101)

typedef _Float16 f16x8 __attribute__((ext_vector_type(8)));
typedef float f32x4 __attribute__((ext_vector_type(4)));

// base-4 digit reversal of a 10-bit index (5 digits); involution.
__device__ __forceinline__ int dr4(int x) {
    const int r = (int)(__brev((unsigned)x) >> 22);   // bit-reverse 10 bits
    return ((r & 0x155) << 1) | ((r >> 1) & 0x155);   // swap adjacent bits
}

// Padded LDS index: kills the power-of-2 stride bank conflicts of radix-4
// (qs=4 was 16-way, others 4-way; padded multiplicity <=2, which is free).
__device__ __forceinline__ int PD(int i) { return i + (i >> 4) + (i >> 6); }

// w = (cos, sin); multiply v by exp(dir*i*theta).
__device__ __forceinline__ float2 cmulw(float2 v, float2 w, float dir) {
    const float wi = dir * w.y;
    return make_float2(v.x * w.x - v.y * wi, v.x * wi + v.y * w.x);
}

// radix-4 combine: y_q = sum_m x_m * W4^{q*m}, W4 = exp(dir*i*pi/2).
__device__ __forceinline__ void r4c(const float2 x0, const float2 x1,
                                    const float2 x2, const float2 x3,
                                    const float dir,
                                    float2& y0, float2& y1, float2& y2, float2& y3) {
    const float ax = x0.x + x2.x, ay = x0.y + x2.y;
    const float bx = x0.x - x2.x, by = x0.y - x2.y;
    const float cx = x1.x + x3.x, cy = x1.y + x3.y;
    const float dx = x1.x - x3.x, dy = x1.y - x3.y;
    y0 = make_float2(ax + cx, ay + cy);
    y2 = make_float2(ax - cx, ay - cy);
    y1 = make_float2(bx - dir * dy, by + dir * dx);
    y3 = make_float2(bx + dir * dy, by - dir * dx);
}

// Twiddle table at padded slots: tw[PD(k)] = (cos, sin)(2*pi*k/1024).
__device__ __forceinline__ void fill_tw(float2* tw, int t) {
    for (int i = t; i < 1024; i += 256) {
        float sv, cv;
        sincosf(6.283185307179586f * (float)i / 1024.0f, &sv, &cv);
        tw[PD(i)] = make_float2(cv, sv);
    }
}

// Radix-4 DIT, padded: digit-reversed input -> natural output. 5 barriers.
__device__ __forceinline__ void fft_dit4p(float2* z, const float2* tw, int t, float dir) {
    #pragma unroll
    for (int st = 0; st < 5; ++st) {
        const int l2q = 2 * st, qs = 1 << l2q;
        const int pos = t & (qs - 1);
        const int base = ((t >> l2q) << (l2q + 2)) + pos;
        const int i0 = PD(base), i1 = PD(base + qs), i2 = PD(base + 2 * qs), i3 = PD(base + 3 * qs);
        float2 x0 = z[i0], x1 = z[i1], x2 = z[i2], x3 = z[i3];
        if (st) {
            const int step = 1 << (8 - l2q);
            const float2 w1 = tw[PD(pos * step)];
            const float2 w2 = tw[PD(2 * pos * step)];
            const float2 w3 = tw[PD(3 * pos * step)];
            x1 = cmulw(x1, w1, dir); x2 = cmulw(x2, w2, dir); x3 = cmulw(x3, w3, dir);
        }
        float2 y0, y1, y2, y3;
        r4c(x0, x1, x2, x3, dir, y0, y1, y2, y3);
        z[i0] = y0; z[i1] = y1; z[i2] = y2; z[i3] = y3;
        __syncthreads();
    }
}

// Radix-4 DIF, padded: natural input -> digit-reversed output. 5 barriers.
__device__ __forceinline__ void fft_dif4p(float2* z, const float2* tw, int t, float dir) {
    #pragma unroll
    for (int st = 4; st >= 0; --st) {
        const int l2q = 2 * st, qs = 1 << l2q;
        const int pos = t & (qs - 1);
        const int base = ((t >> l2q) << (l2q + 2)) + pos;
        const int i0 = PD(base), i1 = PD(base + qs), i2 = PD(base + 2 * qs), i3 = PD(base + 3 * qs);
        const float2 x0 = z[i0], x1 = z[i1], x2 = z[i2], x3 = z[i3];
        float2 s0, s1, s2, s3;
        r4c(x0, x1, x2, x3, dir, s0, s1, s2, s3);
        if (st) {
            const int step = 1 << (8 - l2q);
            const float2 w1 = tw[PD(pos * step)];
            const float2 w2 = tw[PD(2 * pos * step)];
            const float2 w3 = tw[PD(3 * pos * step)];
            s1 = cmulw(s1, w1, dir); s2 = cmulw(s2, w2, dir); s3 = cmulw(s3, w3, dir);
        }
        z[i0] = s0; z[i1] = s1; z[i2] = s2; z[i3] = s3;
        __syncthreads();
    }
}

// Kernel 0: qninv for Q rows; K rows -> unit-normalized f16 (Kh).
__global__ __launch_bounds__(256) void k_prep(const float* __restrict__ Q,
                                              const float* __restrict__ K,
                                              float* __restrict__ qninv,
                                              _Float16* __restrict__ Kh) {
    const int n = B_ * L_ * H_;
    const int i = blockIdx.x * 256 + threadIdx.x;
    if (i >= 2 * n) return;
    const float* p = (i < n) ? (Q + (size_t)i * E_) : (K + (size_t)(i - n) * E_);
    float ss = 0.0f;
    #pragma unroll
    for (int j = 0; j < 16; ++j) {
        const float4 v = *(const float4*)(p + j * 4);
        ss += v.x * v.x + v.y * v.y + v.z * v.z + v.w * v.w;
    }
    const float r = rsqrtf(ss);
    if (i < n) {
        qninv[i] = r;
    } else {
        _Float16* out = Kh + (size_t)(i - n) * E_;
        #pragma unroll
        for (int e = 0; e < E_; e += 8) {
            const float4 x = *(const float4*)(p + e);
            const float4 y = *(const float4*)(p + e + 4);
            f16x8 o;
            o[0] = (_Float16)(x.x * r); o[1] = (_Float16)(x.y * r);
            o[2] = (_Float16)(x.z * r); o[3] = (_Float16)(x.w * r);
            o[4] = (_Float16)(y.x * r); o[5] = (_Float16)(y.y * r);
            o[6] = (_Float16)(y.z * r); o[7] = (_Float16)(y.w * r);
            *(f16x8*)(out + e) = o;
        }
    }
}

// Kernel 1: block = one (b,h) x 16 q-rows. QK^T via mfma_f32_16x16x32_f16
// (slot j loads K row dr4(j) -> radix-4 DIT input store is linear).
// FFT phase: 2 rounds x FOUR concurrent pair-FFTs (8 q-rows/round) in padded
// buffers; per-row softmax max = DC bin (sim>0 => Re F[k] <= F[0], and bin 0
// IS the true max the reference subtracts) -> no max reduction at all.
// ~15 barriers/block vs 32 (round 8) vs 114 (round 7).
__global__ __attribute__((amdgpu_flat_work_group_size(256, 256), amdgpu_waves_per_eu(2, 3)))
void k_qkfft(const float* __restrict__ Q,
             const _Float16* __restrict__ Kh,
             const float* __restrict__ qninv,
             float* __restrict__ G) {
    __shared__ float2 s_z[4 * ZP_];   // 4 padded FFT buffers (35.3 KB)
    __shared__ float2 s_tw[ZP_];      // padded twiddles (8.8 KB)
    __shared__ float s_acc[NF_];
    __shared__ float s_red[32];

    const int t = threadIdx.x;
    const int bid = blockIdx.x;
    const int bh = bid >> 6;        // consecutive blocks share (b,h) -> L2 reuse of Kh
    const int chunk = bid & 63;
    const int b = bh >> 3, h = bh & 7;
    const int l0 = chunk * 16;

    const int c = t & 15;           // A-row / B-col within 16-tile
    const int g = (t >> 4) & 3;     // k-group of the fragment / acc row-group
    const int w = t >> 6;           // wave id (slots [w*256, w*256+256))

    fill_tw(s_tw, t);
    for (int kk = t; kk < NF_; kk += 256) s_acc[kk] = 0.0f;

    // ---- A fragments: q-row (l0+c), normalized, f16, on the fly ----
    const float qn = qninv[((size_t)b * L_ + l0 + c) * H_ + h];
    const float* qrow = Q + (((size_t)b * L_ + l0 + c) * H_ + h) * E_;
    f16x8 af0, af1;
    {
        const float4 x0 = *(const float4*)(qrow + g * 8);
        const float4 y0 = *(const float4*)(qrow + g * 8 + 4);
        af0[0] = (_Float16)(x0.x * qn); af0[1] = (_Float16)(x0.y * qn);
        af0[2] = (_Float16)(x0.z * qn); af0[3] = (_Float16)(x0.w * qn);
        af0[4] = (_Float16)(y0.x * qn); af0[5] = (_Float16)(y0.y * qn);
        af0[6] = (_Float16)(y0.z * qn); af0[7] = (_Float16)(y0.w * qn);
        const float4 x1 = *(const float4*)(qrow + 32 + g * 8);
        const float4 y1 = *(const float4*)(qrow + 32 + g * 8 + 4);
        af1[0] = (_Float16)(x1.x * qn); af1[1] = (_Float16)(x1.y * qn);
        af1[2] = (_Float16)(x1.z * qn); af1[3] = (_Float16)(x1.w * qn);
        af1[4] = (_Float16)(y1.x * qn); af1[5] = (_Float16)(y1.y * qn);
        af1[6] = (_Float16)(y1.z * qn); af1[7] = (_Float16)(y1.w * qn);
    }

    // ---- B fragments + MFMA: 16 N-tiles, 2 k-steps each ----
    f32x4 acc[16];
    #pragma unroll
    for (int n = 0; n < 16; ++n) acc[n] = (f32x4){0.0f, 0.0f, 0.0f, 0.0f};

    #pragma unroll
    for (int n = 0; n < 16; ++n) {
        const int j = w * 256 + n * 16 + c;
        const int s = dr4(j);
        const f16x8* bp = (const f16x8*)(Kh + (((size_t)b * L_ + s) * H_ + h) * E_);
        const f16x8 b0 = bp[g];
        const f16x8 b1 = bp[4 + g];
        acc[n] = __builtin_amdgcn_mfma_f32_16x16x32_f16(af0, b0, acc[n], 0, 0, 0);
        acc[n] = __builtin_amdgcn_mfma_f32_16x16x32_f16(af1, b1, acc[n], 0, 0, 0);
        if ((n & 3) == 3) __builtin_amdgcn_sched_barrier(0);  // fence load hoisting
    }

    // sim = exp(cos) in place
    #pragma unroll
    for (int n = 0; n < 16; ++n) {
        #pragma unroll
        for (int r = 0; r < 4; ++r) acc[n][r] = __expf(acc[n][r]);
    }

    const int lane = t & 63, wid = t >> 6;
    const float dir = -1.0f;

    // ---- 2 rounds x (4 concurrent pair-FFTs + fused 8-row softmax) ----
    #pragma unroll
    for (int rr = 0; rr < 2; ++rr) {
        // scatter: q-rows 8rr..8rr+7. Buffer 2*gq+j <- lanes g==2rr+gq,
        // elems (2j, 2j+1). 16 active lanes/wave/buffer, contiguous slots.
        {
            const int gq = g - 2 * rr;
            if (gq == 0 || gq == 1) {
                float2* z01 = s_z + (2 * gq) * ZP_;
                #pragma unroll
                for (int n = 0; n < 16; ++n) {
                    const int ps = PD(w * 256 + n * 16 + c);
                    z01[ps]       = make_float2(acc[n][0], acc[n][1]);
                    z01[ZP_ + ps] = make_float2(acc[n][2], acc[n][3]);
                }
            }
        }
        __syncthreads();

        // quad radix-4 DIT (digit-reversed in -> natural out), 5 barriers
        #pragma unroll
        for (int st = 0; st < 5; ++st) {
            const int l2q = 2 * st, qs = 1 << l2q;
            const int pos = t & (qs - 1);
            const int base = ((t >> l2q) << (l2q + 2)) + pos;
            const int i0 = PD(base), i1 = PD(base + qs), i2 = PD(base + 2 * qs), i3 = PD(base + 3 * qs);
            float2 w1, w2, w3;
            if (st) {
                const int step = 1 << (8 - l2q);
                w1 = s_tw[PD(pos * step)];
                w2 = s_tw[PD(2 * pos * step)];
                w3 = s_tw[PD(3 * pos * step)];
            }
            #pragma unroll
            for (int q = 0; q < 4; ++q) {
                float2* z = s_z + q * ZP_;
                float2 x0 = z[i0], x1 = z[i1], x2 = z[i2], x3 = z[i3];
                if (st) { x1 = cmulw(x1, w1, dir); x2 = cmulw(x2, w2, dir); x3 = cmulw(x3, w3, dir); }
                float2 y0, y1, y2, y3;
                r4c(x0, x1, x2, x3, dir, y0, y1, y2, y3);
                z[i0] = y0; z[i1] = y1; z[i2] = y2; z[i3] = y3;
            }
            __syncthreads();
        }

        // extraction: 8 rows; softmax max = DC bin (exact), no max reduce
        const int iT = PD(t), iTn = PD((N_ - t) & (N_ - 1));
        const int iU = PD(t + 256), iUn = PD(768 - t);
        float v[8][2], mx[8], p[8][2], pm[8], sm[8];
        #pragma unroll
        for (int q = 0; q < 4; ++q) {
            const float2* z = s_z + q * ZP_;
            const float2 X0 = z[iT], X0n = z[iTn], X1 = z[iU], X1n = z[iUn];
            const float2 DC = z[0];                 // PD(0)==0, broadcast
            const float2 XN = z[PD(512)];           // Nyquist bin (used @t0)
            v[2 * q][0]     = SCALE_ * 0.5f * (X0.x + X0n.x);
            v[2 * q][1]     = SCALE_ * 0.5f * (X1.x + X1n.x);
            v[2 * q + 1][0] = SCALE_ * 0.5f * (X0.y + X0n.y);
            v[2 * q + 1][1] = SCALE_ * 0.5f * (X1.y + X1n.y);
            mx[2 * q]     = SCALE_ * DC.x;
            mx[2 * q + 1] = SCALE_ * DC.y;
            pm[2 * q]     = __expf(SCALE_ * XN.x - mx[2 * q]);
            pm[2 * q + 1] = __expf(SCALE_ * XN.y - mx[2 * q + 1]);
        }
        #pragma unroll
        for (int q = 0; q < 8; ++q) {
            p[q][0] = __expf(v[q][0] - mx[q]);
            p[q][1] = __expf(v[q][1] - mx[q]);
            sm[q] = p[q][0] + p[q][1] + ((t == 0) ? pm[q] : 0.0f);
        }
        #pragma unroll
        for (int off = 32; off > 0; off >>= 1) {
            #pragma unroll
            for (int q = 0; q < 8; ++q) sm[q] += __shfl_xor(sm[q], off);
        }
        if (lane == 0) {
            #pragma unroll
            for (int q = 0; q < 8; ++q) s_red[4 * q + wid] = sm[q];
        }
        __syncthreads();
        float add0 = 0.0f, add1 = 0.0f, addm = 0.0f;
        #pragma unroll
        for (int q = 0; q < 8; ++q) {
            const float inv = 1.0f / (s_red[4 * q] + s_red[4 * q + 1] +
                                      s_red[4 * q + 2] + s_red[4 * q + 3]);
            add0 += p[q][0] * inv;
            add1 += p[q][1] * inv;
            addm += pm[q] * inv;
        }
        s_acc[t]       += add0;
        s_acc[t + 256] += add1;
        if (t == 0) s_acc[512] += addm;
        __syncthreads();   // s_acc/extraction reads done before next scatter
    }

    float* Gp = G + (size_t)bh * NF_;
    for (int kk = t; kk < NF_; kk += 256) atomicAdd(&Gp[kk], s_acc[kk]);
}

// Kernel 2: A[b,h,:] = softmax(G[b,h,:]) over 513 bins.
__global__ __launch_bounds__(256) void k_softA(const float* __restrict__ G,
                                               float* __restrict__ A) {
    __shared__ float s_red[16];
    const int bh = blockIdx.x, t = threadIdx.x;
    const float* Gp = G + (size_t)bh * NF_;
    const float g0 = Gp[t];
    const float g1 = Gp[t + 256];
    const float g2 = (t == 0) ? Gp[512] : -1e30f;
    float m = fmaxf(fmaxf(g0, g1), g2);
    #pragma unroll
    for (int off = 32; off > 0; off >>= 1) m = fmaxf(m, __shfl_xor(m, off));
    const int lane = t & 63, wid = t >> 6;
    if (lane == 0) s_red[wid] = m;
    __syncthreads();
    m = fmaxf(fmaxf(s_red[0], s_red[1]), fmaxf(s_red[2], s_red[3]));
    const float p0 = __expf(g0 - m), p1 = __expf(g1 - m);
    const float p2 = (t == 0) ? __expf(g2 - m) : 0.0f;
    float s = p0 + p1 + p2;
    #pragma unroll
    for (int off = 32; off > 0; off >>= 1) s += __shfl_xor(s, off);
    __syncthreads();
    if (lane == 0) s_red[4 + wid] = s;
    __syncthreads();
    s = s_red[4] + s_red[5] + s_red[6] + s_red[7];
    const float inv = 1.0f / s;
    float* Ap = A + (size_t)bh * NF_;
    Ap[t] = p0 * inv;
    Ap[t + 256] = p1 * inv;
    if (t == 0) Ap[512] = p2 * inv;
}

// Kernel 3: block = one (b,h) x 2 e-channels. Stage V at padded dr4 slots,
// radix-4 DIT fwd -> natural X; Hermitian manipulation in natural order;
// radix-4 DIF inverse (natural -> digit-reversed); write Out[l=dr4(pos)].
__global__ __launch_bounds__(256) void k_vfft(const float* __restrict__ V,
                                              const float* __restrict__ A,
                                              float* __restrict__ Out) {
    __shared__ float2 s_z[ZP_];
    __shared__ float2 s_w[ZP_];
    __shared__ float2 s_tw[ZP_];
    __shared__ float s_A[NF_];

    const int t = threadIdx.x;
    const int bid = blockIdx.x;
    const int bh = bid >> 5, ep = bid & 31;
    const int b = bh >> 3, h = bh & 7;
    const int e0 = ep * 2;

    fill_tw(s_tw, t);
    for (int kk = t; kk < NF_; kk += 256) s_A[kk] = A[(size_t)bh * NF_ + kk];
    #pragma unroll
    for (int jj = 0; jj < 4; ++jj) {
        const int s = jj * 256 + t;
        const float* vp = V + (((size_t)b * L_ + s) * H_ + h) * E_ + e0;
        s_z[PD(dr4(s))] = make_float2(vp[0], vp[1]);
    }
    __syncthreads();

    fft_dit4p(s_z, s_tw, t, -1.0f);   // natural-order X

    #pragma unroll
    for (int jj = 0; jj < 4; ++jj) {
        const int k = jj * 256 + t;
        const int m = (k <= 512) ? k : (N_ - k);
        const float sgn = (k <= 512) ? 1.0f : -1.0f;
        const int mp = (N_ - m) & (N_ - 1);
        const float2 X1 = s_z[PD(m)];
        const float2 X2 = s_z[PD(mp)];
        const float reV1 = 0.5f * (X1.x + X2.x);
        const float imV1 = 0.5f * (X1.y - X2.y);
        const float reV2 = 0.5f * (X1.y + X2.y);
        const float imV2 = 0.5f * (X2.x - X1.x);
        const float a = s_A[m];
        s_w[PD(k)] = make_float2(a * reV1 - sgn * imV2, sgn * imV1 + a * reV2);
    }
    __syncthreads();

    fft_dif4p(s_w, s_tw, t, +1.0f);   // unnormalized inverse, digit-reversed out

    const float invN = 1.0f / (float)N_;
    #pragma unroll
    for (int jj = 0; jj < 4; ++jj) {
        const int p = jj * 256 + t;
        const int l = dr4(p);
        const float2 r = s_w[PD(p)];
        const size_t o = (((size_t)b * L_ + l) * E_ + e0) * H_ + h;
        Out[o] = r.x * invN;        // e0   -> Re
        Out[o + H_] = r.y * invN;   // e0+1 -> Im
    }
}

extern "C" void kernel_launch(void* const* d_in, const int* in_sizes, int n_in,
                              void* d_out, int out_size, void* d_ws, size_t ws_size,
                              hipStream_t stream) {
    const float* Q = (const float*)d_in[0];
    const float* K = (const float*)d_in[1];
    const float* V = (const float*)d_in[2];
    float* out = (float*)d_out;

    float* ws = (float*)d_ws;
    float* qninv   = ws;                                   // B*L*H floats
    _Float16* Kh   = (_Float16*)(ws + B_ * L_ * H_);       // B*L*H*E halves (4 MB)
    float* G       = ws + B_ * L_ * H_ + (B_ * L_ * H_ * E_) / 2;
    float* A       = G + B_ * H_ * NF_;

    hipMemsetAsync(G, 0, (size_t)B_ * H_ * NF_ * sizeof(float), stream);
    k_prep<<<(2 * B_ * L_ * H_ + 255) / 256, 256, 0, stream>>>(Q, K, qninv, Kh);
    k_qkfft<<<B_ * H_ * (L_ / 16), 256, 0, stream>>>(Q, Kh, qninv, G);
    k_softA<<<B_ * H_, 256, 0, stream>>>(G, A);
    k_vfft<<<B_ * H_ * (E_ / 2), 256, 0, stream>>>(V, A, out);
}